// Round 10
// baseline (1547.536 us; speedup 1.0000x reference)
//
#include <hip/hip_runtime.h>
#include <math.h>

// ---------------------------------------------------------------------------
// InvKin, fp32-VALU pipeline with bf16 z-materialization (R9).
// Evidence R4-R8: one row/thread with float h[64] (256 B) promotes to regs;
// ANY 2-row variant (512 B h state) spills at a hard ~128-VGPR ceiling the
// occupancy attributes cannot move. R9 therefore keeps 1 row/thread and
// attacks R4's real overhead (chunked scalar weight loads + lgkmcnt stalls):
// W2/W3 are staged in LDS (16 KB) once per block and read via ds_read_b128
// at wave-uniform addresses (broadcast, conflict-free), overlapping the LDS
// pipe with the FMA pipe.
//   P1 k_stats_x : x second moments (layer-1 BN stats analytic)
//   P2 k_fin1    : fold BN1 -> fp32 W1p[64][3] + c1[64]
//   P3 k_z2      : h1 -> raw z2 -> bf16 zbuf[B][64]   (LDS W2)
//   P4 k_colstats: coalesced per-unit sum/ssq of zbuf
//   P5 k_fin_bn  : s2,c2
//   P6 k_z3      : h2 = relu(s2*z2+c2); z3 = W3 h2 + b3 in place (LDS W3)
//   P7 k_colstats: stats of z3
//   P8 k_fin_bn  : s3,c3
//   P9 k_final   : h3 -> head (192 MACs) -> closed-form FK -> out
// Fallback path (small ws): exact R1 kernel set (verified PASS).
// ---------------------------------------------------------------------------

static constexpr float kEps = 1e-5f;

// shared ws fp32 indices (both paths)
#define WS_STAT9 0
#define WS_SUM2  16
#define WS_SSQ2  80
#define WS_SUM3  144
#define WS_SSQ3  208
#define WS_W1P   288    // [64][3] fp32 (BN1-folded)
#define WS_C1    480    // [64]
// fast path only
#define FP_S2    8192
#define FP_C2    8256
#define FP_S3    8320
#define FP_C3    8384
// fallback (R1) only — may overlap FP_* since only one path ever runs
#define RC_W2P   544
#define RC_C2    4640
#define RC_W3P   4704
#define RC_C3    8800
// z buffer: byte offset 65536 (ushort index 32768)
#define ZB_U16   32768

__device__ __forceinline__ unsigned short f2bf(float f) {
  unsigned u = __builtin_bit_cast(unsigned, f);
  u += 0x7fffu + ((u >> 16) & 1u);
  return (unsigned short)(u >> 16);
}
__device__ __forceinline__ unsigned packbf2(float a, float b) {
  return (unsigned)f2bf(a) | ((unsigned)f2bf(b) << 16);
}
__device__ __forceinline__ void unpack2(unsigned w, float& lo, float& hi) {
  lo = __builtin_bit_cast(float, w << 16);
  hi = __builtin_bit_cast(float, w & 0xffff0000u);
}
__device__ __forceinline__ float bfbits(unsigned short s) {
  unsigned u = ((unsigned)s) << 16;
  return __builtin_bit_cast(float, u);
}

__device__ __forceinline__ float wred64(float v) {
  v += __shfl_xor(v, 32, 64);
  v += __shfl_xor(v, 16, 64);
  v += __shfl_xor(v, 8, 64);
  v += __shfl_xor(v, 4, 64);
  v += __shfl_xor(v, 2, 64);
  v += __shfl_xor(v, 1, 64);
  return v;
}

__device__ __forceinline__ float dot64(const float* __restrict__ wr,
                                       const float hin[64]) {
  float a0 = 0.f, a1 = 0.f, a2 = 0.f, a3 = 0.f;
#pragma unroll
  for (int k = 0; k < 64; k += 4) {
    a0 = fmaf(wr[k + 0], hin[k + 0], a0);
    a1 = fmaf(wr[k + 1], hin[k + 1], a1);
    a2 = fmaf(wr[k + 2], hin[k + 2], a2);
    a3 = fmaf(wr[k + 3], hin[k + 3], a3);
  }
  return (a0 + a1) + (a2 + a3);
}

// 64x64 GEMV vs LDS-resident weights; h in registers; 8-unit blocks.
// Weight reads are wave-uniform -> LDS broadcast (no bank conflicts).
__device__ __forceinline__ void dense64_lds(const float* __restrict__ Wl,
                                            const float* __restrict__ bias,
                                            const float h[64], float zout[64]) {
#pragma unroll 1
  for (int jb = 0; jb < 8; ++jb) {
    float a[8];
#pragma unroll
    for (int u = 0; u < 8; ++u) a[u] = bias[jb * 8 + u];
#pragma unroll 4
    for (int kq = 0; kq < 16; ++kq) {
      float h0 = h[kq * 4 + 0], h1 = h[kq * 4 + 1];
      float h2 = h[kq * 4 + 2], h3 = h[kq * 4 + 3];
#pragma unroll
      for (int u = 0; u < 8; ++u) {
        const float4 w = *(const float4*)&Wl[(jb * 8 + u) * 64 + kq * 4];
        a[u] = fmaf(w.x, h0, fmaf(w.y, h1, fmaf(w.z, h2, fmaf(w.w, h3, a[u]))));
      }
    }
#pragma unroll
    for (int u = 0; u < 8; ++u) zout[jb * 8 + u] = a[u];
  }
}

// ---- P1: x second moments (shared) ---------------------------------------
__global__ void __launch_bounds__(256) k_stats_x(const float* __restrict__ x,
                                                 float* __restrict__ ws, int B) {
  int tid = blockIdx.x * 256 + threadIdx.x;
  int nt = gridDim.x * 256;
  float s0 = 0.f, s1 = 0.f, s2 = 0.f;
  float q00 = 0.f, q01 = 0.f, q02 = 0.f, q11 = 0.f, q12 = 0.f, q22 = 0.f;
  for (int r = tid; r < B; r += nt) {
    float x0 = x[3 * r], x1 = x[3 * r + 1], x2 = x[3 * r + 2];
    s0 += x0; s1 += x1; s2 += x2;
    q00 = fmaf(x0, x0, q00); q01 = fmaf(x0, x1, q01); q02 = fmaf(x0, x2, q02);
    q11 = fmaf(x1, x1, q11); q12 = fmaf(x1, x2, q12); q22 = fmaf(x2, x2, q22);
  }
  s0 = wred64(s0); s1 = wred64(s1); s2 = wred64(s2);
  q00 = wred64(q00); q01 = wred64(q01); q02 = wred64(q02);
  q11 = wred64(q11); q12 = wred64(q12); q22 = wred64(q22);
  __shared__ float part[9];
  if (threadIdx.x < 9) part[threadIdx.x] = 0.f;
  __syncthreads();
  if ((threadIdx.x & 63) == 0) {
    atomicAdd(&part[0], s0); atomicAdd(&part[1], s1); atomicAdd(&part[2], s2);
    atomicAdd(&part[3], q00); atomicAdd(&part[4], q01); atomicAdd(&part[5], q02);
    atomicAdd(&part[6], q11); atomicAdd(&part[7], q12); atomicAdd(&part[8], q22);
  }
  __syncthreads();
  if (threadIdx.x < 9) atomicAdd(&ws[WS_STAT9 + threadIdx.x], part[threadIdx.x]);
}

// ---- P2: fold BN1 (shared) ------------------------------------------------
__global__ void k_fin1(const float* __restrict__ W1, const float* __restrict__ b1,
                       const float* __restrict__ g1, const float* __restrict__ be1,
                       float* __restrict__ ws, int B) {
  int j = threadIdx.x;  // 64
  float inv = 1.0f / (float)B;
  float ex0 = ws[0] * inv, ex1 = ws[1] * inv, ex2 = ws[2] * inv;
  float c00 = ws[3] * inv - ex0 * ex0;
  float c01 = ws[4] * inv - ex0 * ex1;
  float c02 = ws[5] * inv - ex0 * ex2;
  float c11 = ws[6] * inv - ex1 * ex1;
  float c12 = ws[7] * inv - ex1 * ex2;
  float c22 = ws[8] * inv - ex2 * ex2;
  float w0 = W1[3 * j], w1 = W1[3 * j + 1], w2 = W1[3 * j + 2];
  float mean = w0 * ex0 + w1 * ex1 + w2 * ex2 + b1[j];
  float var = w0 * w0 * c00 + w1 * w1 * c11 + w2 * w2 * c22 +
              2.f * (w0 * w1 * c01 + w0 * w2 * c02 + w1 * w2 * c12);
  float s = g1[j] * rsqrtf(var + kEps);
  ws[WS_W1P + 3 * j + 0] = s * w0;
  ws[WS_W1P + 3 * j + 1] = s * w1;
  ws[WS_W1P + 3 * j + 2] = s * w2;
  ws[WS_C1 + j] = fmaf(s, b1[j] - mean, be1[j]);
}

// =========================== FAST PATH =====================================

// ---- P3: z2 = W2 h1 + b2 -> bf16 zbuf (1 row/thread, LDS weights) --------
__global__ void __launch_bounds__(256) k_z2(const float* __restrict__ x,
                                            const float* __restrict__ W2,
                                            const float* __restrict__ b2,
                                            const float* __restrict__ ws,
                                            unsigned short* __restrict__ zb, int B) {
  __shared__ float Wl[4096];
  {
    const float4* Wg = (const float4*)W2;
    float4* Wl4 = (float4*)Wl;
    for (int i = threadIdx.x; i < 1024; i += 256) Wl4[i] = Wg[i];
  }
  __syncthreads();
  const float* W1p = ws + WS_W1P;
  const float* c1 = ws + WS_C1;
  int tid = blockIdx.x * 256 + threadIdx.x;
  int nt = gridDim.x * 256;
  for (int r = tid; r < B; r += nt) {
    float x0 = x[3 * r], x1 = x[3 * r + 1], x2 = x[3 * r + 2];
    float h[64];
#pragma unroll
    for (int k = 0; k < 64; ++k) {
      float z = fmaf(W1p[3 * k + 2], x2,
                 fmaf(W1p[3 * k + 1], x1, fmaf(W1p[3 * k], x0, c1[k])));
      h[k] = fmaxf(z, 0.f);
    }
    float zo[64];
    dense64_lds(Wl, b2, h, zo);
    uint4* zrow = (uint4*)(zb + (size_t)r * 64);
#pragma unroll
    for (int jb = 0; jb < 8; ++jb) {
      uint4 o;
      o.x = packbf2(zo[jb * 8 + 0], zo[jb * 8 + 1]);
      o.y = packbf2(zo[jb * 8 + 2], zo[jb * 8 + 3]);
      o.z = packbf2(zo[jb * 8 + 4], zo[jb * 8 + 5]);
      o.w = packbf2(zo[jb * 8 + 6], zo[jb * 8 + 7]);
      zrow[jb] = o;
    }
  }
}

// ---- P4/P7: coalesced per-unit sum/ssq of zbuf ---------------------------
__global__ void __launch_bounds__(256) k_colstats(const unsigned short* __restrict__ zb,
                                                  float* __restrict__ sumg,
                                                  float* __restrict__ ssqg, int B) {
  int u = threadIdx.x & 63;
  int rloc = threadIdx.x >> 6;              // 0..3
  int rstep = gridDim.x * 4;
  float accS = 0.f, accQ = 0.f;
  for (int r = blockIdx.x * 4 + rloc; r < B; r += rstep) {
    float z = bfbits(zb[(size_t)r * 64 + u]);
    accS += z;
    accQ = fmaf(z, z, accQ);
  }
  __shared__ float sS[64], sQ[64];
  if (threadIdx.x < 64) { sS[threadIdx.x] = 0.f; sQ[threadIdx.x] = 0.f; }
  __syncthreads();
  atomicAdd(&sS[u], accS);
  atomicAdd(&sQ[u], accQ);
  __syncthreads();
  if (threadIdx.x < 64) {
    atomicAdd(&sumg[threadIdx.x], sS[threadIdx.x]);
    atomicAdd(&ssqg[threadIdx.x], sQ[threadIdx.x]);
  }
}

// ---- P5/P8: BN scale/shift only ------------------------------------------
__global__ void k_fin_bn(const float* __restrict__ sum, const float* __restrict__ ssq,
                         const float* __restrict__ g, const float* __restrict__ be,
                         float* __restrict__ sOut, float* __restrict__ cOut, int B) {
  int j = threadIdx.x;  // 64
  float inv = 1.0f / (float)B;
  float mean = sum[j] * inv;
  float var = ssq[j] * inv - mean * mean;
  float s = g[j] * rsqrtf(var + kEps);
  sOut[j] = s;
  cOut[j] = fmaf(-s, mean, be[j]);
}

// ---- P6: z3 = W3 relu(s2*z2+c2) + b3, in place (LDS weights) -------------
__global__ void __launch_bounds__(256) k_z3(const float* __restrict__ W3,
                                            const float* __restrict__ b3,
                                            const float* __restrict__ ws,
                                            unsigned short* __restrict__ zb, int B) {
  __shared__ float Wl[4096];
  {
    const float4* Wg = (const float4*)W3;
    float4* Wl4 = (float4*)Wl;
    for (int i = threadIdx.x; i < 1024; i += 256) Wl4[i] = Wg[i];
  }
  __syncthreads();
  const float* s2 = ws + FP_S2;
  const float* c2 = ws + FP_C2;
  int tid = blockIdx.x * 256 + threadIdx.x;
  int nt = gridDim.x * 256;
  for (int r = tid; r < B; r += nt) {
    uint4* zrow = (uint4*)(zb + (size_t)r * 64);
    float h[64];
#pragma unroll
    for (int jb = 0; jb < 8; ++jb) {
      uint4 v = zrow[jb];
      int k = jb * 8;
      unpack2(v.x, h[k + 0], h[k + 1]);
      unpack2(v.y, h[k + 2], h[k + 3]);
      unpack2(v.z, h[k + 4], h[k + 5]);
      unpack2(v.w, h[k + 6], h[k + 7]);
    }
#pragma unroll
    for (int k = 0; k < 64; ++k)
      h[k] = fmaxf(fmaf(s2[k], h[k], c2[k]), 0.f);
    float zo[64];
    dense64_lds(Wl, b3, h, zo);
#pragma unroll
    for (int jb = 0; jb < 8; ++jb) {
      uint4 o;
      o.x = packbf2(zo[jb * 8 + 0], zo[jb * 8 + 1]);
      o.y = packbf2(zo[jb * 8 + 2], zo[jb * 8 + 3]);
      o.z = packbf2(zo[jb * 8 + 4], zo[jb * 8 + 5]);
      o.w = packbf2(zo[jb * 8 + 6], zo[jb * 8 + 7]);
      zrow[jb] = o;
    }
  }
}

// ---- P9: h3 -> head -> FK -> out (1 row/thread) ---------------------------
__global__ void __launch_bounds__(256) k_final_fast(const unsigned short* __restrict__ zb,
                                                    const float* __restrict__ W4,
                                                    const float* __restrict__ b4,
                                                    const float* __restrict__ ws,
                                                    float* __restrict__ out, int B) {
  const float* s3 = ws + FP_S3;
  const float* c3 = ws + FP_C3;
  int tid = blockIdx.x * 256 + threadIdx.x;
  int nt = gridDim.x * 256;
  for (int r = tid; r < B; r += nt) {
    const uint4* zrow = (const uint4*)(zb + (size_t)r * 64);
    float h[64];
#pragma unroll
    for (int jb = 0; jb < 8; ++jb) {
      uint4 v = zrow[jb];
      int k = jb * 8;
      unpack2(v.x, h[k + 0], h[k + 1]);
      unpack2(v.y, h[k + 2], h[k + 3]);
      unpack2(v.z, h[k + 4], h[k + 5]);
      unpack2(v.w, h[k + 6], h[k + 7]);
    }
#pragma unroll
    for (int k = 0; k < 64; ++k)
      h[k] = fmaxf(fmaf(s3[k], h[k], c3[k]), 0.f);
    float t0 = b4[0] + dot64(W4, h);
    float t1 = b4[1] + dot64(W4 + 64, h);
    float t2 = b4[2] + dot64(W4 + 128, h);
    out[3 * r + 0] = t0;
    out[3 * r + 1] = t1;
    out[3 * r + 2] = t2;
    float s0, c0v, s1, c1v, s12, c12;
    sincosf(t0, &s0, &c0v);
    sincosf(t1, &s1, &c1v);
    sincosf(t1 + t2, &s12, &c12);
    float A = fmaf(0.115f, c12, 0.12f * c1v);
    size_t o2 = (size_t)3 * B + 3 * r;
    out[o2 + 0] = c0v * A;
    out[o2 + 1] = s0 * A;
    out[o2 + 2] = fmaf(0.115f, s12, 0.12f * s1);
  }
}

// ========================= FALLBACK (R1, verified) =========================

__device__ __forceinline__ void layer1_eval(const float* __restrict__ W1p,
                                            const float* __restrict__ c1,
                                            float x0, float x1, float x2,
                                            float h[64]) {
#pragma unroll
  for (int j = 0; j < 64; ++j) {
    float z = fmaf(W1p[3 * j + 2], x2,
               fmaf(W1p[3 * j + 1], x1, fmaf(W1p[3 * j], x0, c1[j])));
    h[j] = fmaxf(z, 0.f);
  }
}

__device__ __forceinline__ void dense_relu_rc(const float* __restrict__ Wp,
                                              const float* __restrict__ c,
                                              const float hin[64], float hout[64]) {
#pragma unroll
  for (int j = 0; j < 64; ++j)
    hout[j] = fmaxf(dot64(Wp + j * 64, hin) + c[j], 0.f);
}

__device__ __forceinline__ void dense_stats_rc(const float* __restrict__ W,
                                               const float* __restrict__ b,
                                               const float hin[64], int lane,
                                               float valid, float& accS, float& accQ) {
#pragma unroll 1
  for (int j = 0; j < 64; ++j) {
    float z = (dot64(W + j * 64, hin) + b[j]) * valid;
    float rs = wred64(z);
    float rq = wred64(z * z);
    accS += (lane == j) ? rs : 0.f;
    accQ += (lane == j) ? rq : 0.f;
  }
}

__device__ __forceinline__ void block_combine_rc(float accS, float accQ,
                                                 float* __restrict__ sumg,
                                                 float* __restrict__ ssqg) {
  __shared__ float sS[256], sQ[256];
  sS[threadIdx.x] = accS;
  sQ[threadIdx.x] = accQ;
  __syncthreads();
  if (threadIdx.x < 64) {
    float S = sS[threadIdx.x] + sS[threadIdx.x + 64] + sS[threadIdx.x + 128] + sS[threadIdx.x + 192];
    float Q = sQ[threadIdx.x] + sQ[threadIdx.x + 64] + sQ[threadIdx.x + 128] + sQ[threadIdx.x + 192];
    atomicAdd(&sumg[threadIdx.x], S);
    atomicAdd(&ssqg[threadIdx.x], Q);
  }
}

__global__ void __launch_bounds__(256) k_stats2_rc(const float* __restrict__ x,
                                                   const float* __restrict__ W2,
                                                   const float* __restrict__ b2,
                                                   float* __restrict__ ws, int B) {
  const float* W1p = ws + WS_W1P;
  const float* c1 = ws + WS_C1;
  int tid = blockIdx.x * 256 + threadIdx.x;
  int nt = gridDim.x * 256;
  int lane = threadIdx.x & 63;
  float accS = 0.f, accQ = 0.f;
  int iters = (B + nt - 1) / nt;
  for (int it = 0; it < iters; ++it) {
    int r = tid + it * nt;
    float valid = (r < B) ? 1.f : 0.f;
    int rc = (r < B) ? r : (B - 1);
    float h1[64];
    layer1_eval(W1p, c1, x[3 * rc], x[3 * rc + 1], x[3 * rc + 2], h1);
    dense_stats_rc(W2, b2, h1, lane, valid, accS, accQ);
  }
  block_combine_rc(accS, accQ, ws + WS_SUM2, ws + WS_SSQ2);
}

__global__ void k_fin_dense_rc(const float* __restrict__ W, const float* __restrict__ b,
                               const float* __restrict__ g, const float* __restrict__ be,
                               const float* __restrict__ sum, const float* __restrict__ ssq,
                               float* __restrict__ Wp, float* __restrict__ cc, int B) {
  int j = threadIdx.x;
  float inv = 1.0f / (float)B;
  float mean = sum[j] * inv;
  float var = ssq[j] * inv - mean * mean;
  float s = g[j] * rsqrtf(var + kEps);
  for (int k = 0; k < 64; ++k) Wp[j * 64 + k] = s * W[j * 64 + k];
  cc[j] = fmaf(s, b[j] - mean, be[j]);
}

__global__ void __launch_bounds__(256) k_stats3_rc(const float* __restrict__ x,
                                                   const float* __restrict__ W3,
                                                   const float* __restrict__ b3,
                                                   float* __restrict__ ws, int B) {
  const float* W1p = ws + WS_W1P;
  const float* c1 = ws + WS_C1;
  const float* W2p = ws + RC_W2P;
  const float* c2 = ws + RC_C2;
  int tid = blockIdx.x * 256 + threadIdx.x;
  int nt = gridDim.x * 256;
  int lane = threadIdx.x & 63;
  float accS = 0.f, accQ = 0.f;
  int iters = (B + nt - 1) / nt;
  for (int it = 0; it < iters; ++it) {
    int r = tid + it * nt;
    float valid = (r < B) ? 1.f : 0.f;
    int rc = (r < B) ? r : (B - 1);
    float h1[64], h2[64];
    layer1_eval(W1p, c1, x[3 * rc], x[3 * rc + 1], x[3 * rc + 2], h1);
    dense_relu_rc(W2p, c2, h1, h2);
    dense_stats_rc(W3, b3, h2, lane, valid, accS, accQ);
  }
  block_combine_rc(accS, accQ, ws + WS_SUM3, ws + WS_SSQ3);
}

__global__ void __launch_bounds__(256) k_final_rc(const float* __restrict__ x,
                                                  const float* __restrict__ W4,
                                                  const float* __restrict__ b4,
                                                  const float* __restrict__ ws,
                                                  float* __restrict__ out, int B) {
  const float* W1p = ws + WS_W1P;
  const float* c1 = ws + WS_C1;
  const float* W2p = ws + RC_W2P;
  const float* c2 = ws + RC_C2;
  const float* W3p = ws + RC_W3P;
  const float* c3 = ws + RC_C3;
  int tid = blockIdx.x * 256 + threadIdx.x;
  int nt = gridDim.x * 256;
  for (int r = tid; r < B; r += nt) {
    float h1[64], h2[64];
    layer1_eval(W1p, c1, x[3 * r], x[3 * r + 1], x[3 * r + 2], h1);
    dense_relu_rc(W2p, c2, h1, h2);
    float t0 = b4[0], t1 = b4[1], t2 = b4[2];
#pragma unroll 1
    for (int j = 0; j < 64; ++j) {
      float h3 = fmaxf(dot64(W3p + j * 64, h2) + c3[j], 0.f);
      t0 = fmaf(W4[j], h3, t0);
      t1 = fmaf(W4[64 + j], h3, t1);
      t2 = fmaf(W4[128 + j], h3, t2);
    }
    out[3 * r + 0] = t0;
    out[3 * r + 1] = t1;
    out[3 * r + 2] = t2;
    float s0, c0v, s1, c1v, s12, c12;
    sincosf(t0, &s0, &c0v);
    sincosf(t1, &s1, &c1v);
    sincosf(t1 + t2, &s12, &c12);
    float A = fmaf(0.115f, c12, 0.12f * c1v);
    size_t o2 = (size_t)3 * B + 3 * r;
    out[o2 + 0] = c0v * A;
    out[o2 + 1] = s0 * A;
    out[o2 + 2] = fmaf(0.115f, s12, 0.12f * s1);
  }
}

// ===========================================================================

extern "C" void kernel_launch(void* const* d_in, const int* in_sizes, int n_in,
                              void* d_out, int out_size, void* d_ws, size_t ws_size,
                              hipStream_t stream) {
  const float* x = (const float*)d_in[0];
  const float* W1 = (const float*)d_in[1];
  const float* b1 = (const float*)d_in[2];
  const float* g1 = (const float*)d_in[3];
  const float* be1 = (const float*)d_in[4];
  const float* W2 = (const float*)d_in[5];
  const float* b2 = (const float*)d_in[6];
  const float* g2 = (const float*)d_in[7];
  const float* be2 = (const float*)d_in[8];
  const float* W3 = (const float*)d_in[9];
  const float* b3 = (const float*)d_in[10];
  const float* g3 = (const float*)d_in[11];
  const float* be3 = (const float*)d_in[12];
  const float* W4 = (const float*)d_in[13];
  const float* b4 = (const float*)d_in[14];
  float* ws = (float*)d_ws;
  float* out = (float*)d_out;
  int B = in_sizes[0] / 3;

  hipMemsetAsync(d_ws, 0, 272 * sizeof(float), stream);

  const int blocks = 1024, thr = 256;
  size_t need = 65536 + (size_t)B * 64 * 2;

  k_stats_x<<<blocks, thr, 0, stream>>>(x, ws, B);
  k_fin1<<<1, 64, 0, stream>>>(W1, b1, g1, be1, ws, B);

  if (ws_size >= need) {
    unsigned short* zb = (unsigned short*)ws + ZB_U16;
    k_z2<<<blocks, thr, 0, stream>>>(x, W2, b2, ws, zb, B);
    k_colstats<<<blocks, thr, 0, stream>>>(zb, ws + WS_SUM2, ws + WS_SSQ2, B);
    k_fin_bn<<<1, 64, 0, stream>>>(ws + WS_SUM2, ws + WS_SSQ2, g2, be2,
                                   ws + FP_S2, ws + FP_C2, B);
    k_z3<<<blocks, thr, 0, stream>>>(W3, b3, ws, zb, B);
    k_colstats<<<blocks, thr, 0, stream>>>(zb, ws + WS_SUM3, ws + WS_SSQ3, B);
    k_fin_bn<<<1, 64, 0, stream>>>(ws + WS_SUM3, ws + WS_SSQ3, g3, be3,
                                   ws + FP_S3, ws + FP_C3, B);
    k_final_fast<<<blocks, thr, 0, stream>>>(zb, W4, b4, ws, out, B);
  } else {
    k_stats2_rc<<<blocks, thr, 0, stream>>>(x, W2, b2, ws, B);
    k_fin_dense_rc<<<1, 64, 0, stream>>>(W2, b2, g2, be2, ws + WS_SUM2, ws + WS_SSQ2,
                                         ws + RC_W2P, ws + RC_C2, B);
    k_stats3_rc<<<blocks, thr, 0, stream>>>(x, W3, b3, ws, B);
    k_fin_dense_rc<<<1, 64, 0, stream>>>(W3, b3, g3, be3, ws + WS_SUM3, ws + WS_SSQ3,
                                         ws + RC_W3P, ws + RC_C3, B);
    k_final_rc<<<blocks, thr, 0, stream>>>(x, W4, b4, ws, out, B);
  }
}